// Round 1
// baseline (615.844 us; speedup 1.0000x reference)
//
#include <hip/hip_runtime.h>
#include <hip/hip_bf16.h>

#define N_NODES 10000
#define S_NB 20
#define D_IN 512
#define D_OUT 512
#define ATTEN_D 64
#define KTOT 1024            // 2*D_IN (stacked self|neigh)
#define M_PAD 10048          // 157 * 64 (X allocation; rows >= N_NODES may hold poison)
#define AGG_BLOCKS (N_NODES / 4)
#define TR_BLOCKS 100        // role-split blocks inside aggregate doing the Wt transpose

typedef __bf16 bf16_t;
typedef bf16_t bf16x8 __attribute__((ext_vector_type(8)));
typedef float f32x4 __attribute__((ext_vector_type(4)));
typedef unsigned short u16x8 __attribute__((ext_vector_type(8)));

__device__ __forceinline__ unsigned short f2bf(float f) {
    unsigned int u = __float_as_uint(f);
    unsigned int r = u + 0x7FFFu + ((u >> 16) & 1u);   // RNE
    return (unsigned short)(r >> 16);
}

__device__ __forceinline__ void gl_lds16(const unsigned short* g, unsigned short* l) {
    __builtin_amdgcn_global_load_lds(
        (const __attribute__((address_space(1))) void*)g,
        (__attribute__((address_space(3))) void*)l,
        16, 0, 0);
}

// ---------------------------------------------------------------------------
// Kernel 0 (tiny): u_self = self_atten @ v, u_neigh = neigh_atten @ v.
// This is the only prep that aggregate depends on. 1024 rows, one row per
// wave-iteration, coalesced 64-lane reads + butterfly reduce. ~2-3 us.
// ---------------------------------------------------------------------------
__global__ __launch_bounds__(256) void u_prep_kernel(
        const float* __restrict__ self_atten, const float* __restrict__ neigh_atten,
        const float* __restrict__ v,
        float* __restrict__ u_self, float* __restrict__ u_neigh) {
    const int lane = threadIdx.x & 63;
    const int g = blockIdx.x * 4 + (threadIdx.x >> 6);   // 0..63
    const float vl = v[lane];
    const int r0 = g * 16;
    #pragma unroll
    for (int i = 0; i < 16; ++i) {
        int row = r0 + i;
        const float* src = (row < D_IN) ? (self_atten + (size_t)row * ATTEN_D)
                                        : (neigh_atten + (size_t)(row - D_IN) * ATTEN_D);
        float p = src[lane] * vl;
        #pragma unroll
        for (int off = 32; off > 0; off >>= 1) p += __shfl_xor(p, off, 64);
        if (lane == 0) {
            if (row < D_IN) u_self[row] = p;
            else            u_neigh[row - D_IN] = p;
        }
    }
}

// ---------------------------------------------------------------------------
// Kernel 1: wave-per-node aggregation (unchanged core), PLUS TR_BLOCKS extra
// blocks that perform the Wt cast+transpose — hidden under the HBM-bound
// aggregation phase (adds ~4 MB HBM + ~34 MB L2 traffic vs 430 MB streamed).
// X pad rows are NOT zeroed: GEMM rows map 1:1 to out rows; poison rows only
// feed accumulators whose stores are guarded by R < N_NODES.
// ---------------------------------------------------------------------------
__global__ __launch_bounds__(256) void aggregate_kernel(
        const float* __restrict__ self_vecs, const float* __restrict__ neigh_vecs,
        const float* __restrict__ neigh_weight, const int* __restrict__ neigh_column,
        const float* __restrict__ alpha,
        const float* __restrict__ u_self, const float* __restrict__ u_neigh,
        unsigned short* __restrict__ X,
        const float* __restrict__ neigh_w, const float* __restrict__ self_w,
        unsigned short* __restrict__ Wt) {
    if (blockIdx.x >= AGG_BLOCKS) {
        // --- transpose role: Wt[n][k] = (k<512 ? self_w[k][n] : neigh_w[k-512][n]) ---
        int idx = (blockIdx.x - AGG_BLOCKS) * blockDim.x + threadIdx.x;
        int stride = TR_BLOCKS * 256;
        for (int i = idx; i < D_OUT * KTOT; i += stride) {
            int n = i >> 10;
            int k = i & (KTOT - 1);
            float w = (k < D_IN) ? self_w[k * D_OUT + n] : neigh_w[(k - D_IN) * D_OUT + n];
            Wt[i] = f2bf(w);
        }
        return;
    }

    const int lane = threadIdx.x & 63;
    const int n = blockIdx.x * 4 + (threadIdx.x >> 6);   // N_NODES % 4 == 0

    // --- softmax coefficients (lanes 0..19 hold coef, rest hold 0) ---
    float e = 0.f, wgt = 0.f;
    if (lane < S_NB) {
        e = expf(alpha[neigh_column[n * S_NB + lane]]);
        wgt = neigh_weight[n * S_NB + lane];
    }
    float ssum = e;
    #pragma unroll
    for (int off = 32; off > 0; off >>= 1) ssum += __shfl_xor(ssum, off, 64);
    float coefv = wgt * e / ssum;

    // --- stream 20 neighbor rows, weighted accumulate ---
    const float4* nb = (const float4*)(neigh_vecs + (size_t)n * S_NB * D_IN);
    float4 acc0 = make_float4(0.f, 0.f, 0.f, 0.f);
    float4 acc1 = make_float4(0.f, 0.f, 0.f, 0.f);
    #pragma unroll
    for (int s = 0; s < S_NB; ++s) {
        float c = __shfl(coefv, s, 64);
        float4 x0 = nb[s * 128 + 2 * lane];
        float4 x1 = nb[s * 128 + 2 * lane + 1];
        acc0.x = fmaf(c, x0.x, acc0.x); acc0.y = fmaf(c, x0.y, acc0.y);
        acc0.z = fmaf(c, x0.z, acc0.z); acc0.w = fmaf(c, x0.w, acc0.w);
        acc1.x = fmaf(c, x1.x, acc1.x); acc1.y = fmaf(c, x1.y, acc1.y);
        acc1.z = fmaf(c, x1.z, acc1.z); acc1.w = fmaf(c, x1.w, acc1.w);
    }

    // --- gate dots (butterfly: every lane ends with the full sums) ---
    const float4* svp = (const float4*)(self_vecs + (size_t)n * D_IN);
    float4 sv0 = svp[2 * lane], sv1 = svp[2 * lane + 1];
    float4 us0 = ((const float4*)u_self)[2 * lane];
    float4 us1 = ((const float4*)u_self)[2 * lane + 1];
    float4 un0 = ((const float4*)u_neigh)[2 * lane];
    float4 un1 = ((const float4*)u_neigh)[2 * lane + 1];
    float p1 = sv0.x * us0.x + sv0.y * us0.y + sv0.z * us0.z + sv0.w * us0.w
             + sv1.x * us1.x + sv1.y * us1.y + sv1.z * us1.z + sv1.w * us1.w;
    float p2 = acc0.x * un0.x + acc0.y * un0.y + acc0.z * un0.z + acc0.w * un0.w
             + acc1.x * un1.x + acc1.y * un1.y + acc1.z * un1.z + acc1.w * un1.w;
    #pragma unroll
    for (int off = 32; off > 0; off >>= 1) {
        p1 += __shfl_xor(p1, off, 64);
        p2 += __shfl_xor(p2, off, 64);
    }
    float a_s = expf(tanhf(2.0f * p1));
    float a_n = expf(tanhf(p2 + p1));
    float inv = 1.0f / (a_s + a_n);
    float gs = a_s * inv, gn = a_n * inv;

    // --- write X row: [gs*self | gn*neigh_sum] as bf16, 16 B per store ---
    unsigned short* xrow = X + (size_t)n * KTOT;
    u16x8 o;
    o[0] = f2bf(gs * sv0.x); o[1] = f2bf(gs * sv0.y);
    o[2] = f2bf(gs * sv0.z); o[3] = f2bf(gs * sv0.w);
    o[4] = f2bf(gs * sv1.x); o[5] = f2bf(gs * sv1.y);
    o[6] = f2bf(gs * sv1.z); o[7] = f2bf(gs * sv1.w);
    *(u16x8*)(xrow + 8 * lane) = o;
    o[0] = f2bf(gn * acc0.x); o[1] = f2bf(gn * acc0.y);
    o[2] = f2bf(gn * acc0.z); o[3] = f2bf(gn * acc0.w);
    o[4] = f2bf(gn * acc1.x); o[5] = f2bf(gn * acc1.y);
    o[6] = f2bf(gn * acc1.z); o[7] = f2bf(gn * acc1.w);
    *(u16x8*)(xrow + D_IN + 8 * lane) = o;
}

// ---------------------------------------------------------------------------
// Kernel 2: B-resident single-barrier GEMM. out = relu(X[M,1024] @ Wt^T).
// 256 blocks x 512 threads. Each block owns a 64-col panel of Wt, staged ONCE
// into 128 KB LDS (XOR-swizzled via pre-swizzled global source, linear dest),
// then 8 waves process independent 32-row strips with ZERO further barriers:
// A-frags direct from global (X is L2/L3-hot), B-frags ds_read_b128 swizzled.
// XCD-bijective remap: all 8 col-panels of one M-range land on one XCD so the
// ~640 KB A panel is L2-resident after first touch (8x reuse from L2 not L3).
// ---------------------------------------------------------------------------
__global__ __launch_bounds__(512) void gemm_kernel(
        const unsigned short* __restrict__ X, const unsigned short* __restrict__ Wt,
        float* __restrict__ out) {
    __shared__ __align__(16) unsigned short Bs[64 * KTOT];   // 128 KB

    const int tid = threadIdx.x;
    const int lane = tid & 63;
    const int wid = tid >> 6;
    const int bid = blockIdx.x;
    // bijective remap: same (bid&7) -> same XCD (round-robin dispatch) -> same y
    const int y = (bid & 7) + ((bid >> 3) & 3) * 8;   // 0..31: M-panel group
    const int x = bid >> 5;                            // 0..7 : 64-col panel
    const int n0 = x * 64;
    const int m_base = y * 320;                        // 32 panels x 320 rows >= 10000

    // --- stage B panel: dest linear, source pre-swizzled (involution XOR) ---
    const char* Wb = (const char*)(Wt + (size_t)n0 * KTOT);
    char* Bsb = (char*)Bs;
    #pragma unroll
    for (int r = 0; r < 16; ++r) {
        int chunk = r * 512 + tid;          // 8192 x 16B
        int d = chunk * 16;                 // linear LDS byte (wave-uniform + lane*16)
        int nrow = d >> 11;                 // 2048 B per row
        int rb = d & 2047;
        int src = nrow * 2048 + (rb ^ ((nrow & 7) << 4));
        gl_lds16((const unsigned short*)(Wb + src), (unsigned short*)(Bsb + d));
    }
    __syncthreads();   // compiler drains vmcnt(0) here — B resident from now on

    const int quad = lane >> 4;
    const int mrow = lane & 15;
    const int qb = quad * 16;
    const int swz = (mrow & 7) << 4;        // (row&7)<<4 — row%8 == mrow%8 for all nf
    const char* B0 = Bsb + (size_t)(0 * 16 + mrow) * 2048;
    const char* B1 = Bsb + (size_t)(1 * 16 + mrow) * 2048;
    const char* B2 = Bsb + (size_t)(2 * 16 + mrow) * 2048;
    const char* B3 = Bsb + (size_t)(3 * 16 + mrow) * 2048;
    const char* Xb = (const char*)X;

    #define LDA(D_, KK_) {                                              \
        int ao_ = (KK_) * 2;                                            \
        D_[0] = *(const bf16x8*)(Arow0 + ao_);                          \
        D_[1] = *(const bf16x8*)(Arow1 + ao_); }
    #define LDB(D_, KK_) {                                              \
        int ko_ = (((KK_) * 2) + qb) ^ swz;                             \
        D_[0] = *(const bf16x8*)(B0 + ko_);                             \
        D_[1] = *(const bf16x8*)(B1 + ko_);                             \
        D_[2] = *(const bf16x8*)(B2 + ko_);                             \
        D_[3] = *(const bf16x8*)(B3 + ko_); }
    #define MFMA8(A_, B_)                                               \
        _Pragma("unroll") for (int i_ = 0; i_ < 2; ++i_)                \
        _Pragma("unroll") for (int j_ = 0; j_ < 4; ++j_)                \
            acc[i_][j_] = __builtin_amdgcn_mfma_f32_16x16x32_bf16(      \
                A_[i_], B_[j_], acc[i_][j_], 0, 0, 0);

    // --- strips: 10 per block (y=31: 3), one 32-row strip per wave-task ---
    for (int s = wid; s < 10; s += 8) {
        const int m0 = m_base + s * 32;
        if (m0 >= N_NODES) break;           // reads stay < M_PAD (max row 10015)

        f32x4 acc[2][4];
        f32x4 zero = {0.f, 0.f, 0.f, 0.f};
        #pragma unroll
        for (int i = 0; i < 2; ++i)
            #pragma unroll
            for (int j = 0; j < 4; ++j) acc[i][j] = zero;

        const char* Arow0 = Xb + (size_t)(m0 + mrow) * 2048 + qb;
        const char* Arow1 = Arow0 + 16 * 2048;

        bf16x8 aC[2], bC[4], aN[2], bN[4];
        LDA(aC, 0); LDB(bC, 0);
        for (int k0 = 0; k0 < KTOT; k0 += 64) {
            LDA(aN, k0 + 32); LDB(bN, k0 + 32);    // prefetch next half-step
            MFMA8(aC, bC);
            if (k0 + 64 < KTOT) { LDA(aC, k0 + 64); LDB(bC, k0 + 64); }
            MFMA8(aN, bN);
        }

        // epilogue: C/D layout col=lane&15, row=quad*4+reg
        #pragma unroll
        for (int i = 0; i < 2; ++i) {
            int rbase = m0 + i * 16 + quad * 4;
            #pragma unroll
            for (int j = 0; j < 4; ++j) {
                int c = n0 + j * 16 + mrow;
                #pragma unroll
                for (int r = 0; r < 4; ++r) {
                    int R = rbase + r;
                    if (R < N_NODES)
                        out[(size_t)R * D_OUT + c] = fmaxf(acc[i][j][r], 0.f);
                }
            }
        }
    }
    #undef LDA
    #undef LDB
    #undef MFMA8
}

extern "C" void kernel_launch(void* const* d_in, const int* in_sizes, int n_in,
                              void* d_out, int out_size, void* d_ws, size_t ws_size,
                              hipStream_t stream) {
    const float* self_vecs     = (const float*)d_in[0];
    const float* neigh_vecs    = (const float*)d_in[1];
    const float* neigh_weight  = (const float*)d_in[2];
    const int*   neigh_column  = (const int*)d_in[3];
    const float* neigh_weights = (const float*)d_in[4];
    const float* self_weights  = (const float*)d_in[5];
    const float* alpha         = (const float*)d_in[6];
    const float* self_atten    = (const float*)d_in[7];
    const float* neigh_atten   = (const float*)d_in[8];
    const float* v             = (const float*)d_in[9];
    float* out = (float*)d_out;

    char* ws = (char*)d_ws;
    float* u_self  = (float*)ws;                                   // 512 f32
    float* u_neigh = u_self + D_IN;                                // 512 f32
    unsigned short* Wt = (unsigned short*)(ws + 4096);             // 512*1024 bf16 = 1 MB
    unsigned short* X  = (unsigned short*)(ws + 4096 + (size_t)D_OUT * KTOT * 2); // M_PAD*1024 bf16

    hipLaunchKernelGGL(u_prep_kernel, dim3(16), dim3(256), 0, stream,
                       self_atten, neigh_atten, v, u_self, u_neigh);
    hipLaunchKernelGGL(aggregate_kernel, dim3(AGG_BLOCKS + TR_BLOCKS), dim3(256), 0, stream,
                       self_vecs, neigh_vecs, neigh_weight, neigh_column, alpha,
                       u_self, u_neigh, X, neigh_weights, self_weights, Wt);
    hipLaunchKernelGGL(gemm_kernel, dim3(256), dim3(512), 0, stream, X, Wt, out);
}

// Round 2
// 598.979 us; speedup vs baseline: 1.0282x; 1.0282x over previous
//
#include <hip/hip_runtime.h>
#include <hip/hip_bf16.h>

#define N_NODES 10000
#define S_NB 20
#define D_IN 512
#define D_OUT 512
#define ATTEN_D 64
#define KTOT 1024            // 2*D_IN (stacked self|neigh)
#define M_PAD 10048          // 157 * 64 (X allocation; rows >= N_NODES hold poison, stores guarded)
#define TR_BLOCKS 100        // role-split blocks at grid FRONT doing the Wt transpose
#define AGG_BLOCKS (N_NODES / 4)

typedef __bf16 bf16_t;
typedef bf16_t bf16x8 __attribute__((ext_vector_type(8)));
typedef float f32x4 __attribute__((ext_vector_type(4)));
typedef unsigned short u16x8 __attribute__((ext_vector_type(8)));

__device__ __forceinline__ unsigned short f2bf(float f) {
    unsigned int u = __float_as_uint(f);
    unsigned int r = u + 0x7FFFu + ((u >> 16) & 1u);   // RNE
    return (unsigned short)(r >> 16);
}

__device__ __forceinline__ void gl_lds16(const unsigned short* g, unsigned short* l) {
    __builtin_amdgcn_global_load_lds(
        (const __attribute__((address_space(1))) void*)g,
        (__attribute__((address_space(3))) void*)l,
        16, 0, 0);
}

// ---------------------------------------------------------------------------
// Kernel 0 (tiny, ~2 us): u_self = self_atten @ v, u_neigh = neigh_atten @ v.
// Only prep that aggregate depends on. Coalesced 64-lane reads + butterfly.
// ---------------------------------------------------------------------------
__global__ __launch_bounds__(256) void u_prep_kernel(
        const float* __restrict__ self_atten, const float* __restrict__ neigh_atten,
        const float* __restrict__ v,
        float* __restrict__ u_self, float* __restrict__ u_neigh) {
    const int lane = threadIdx.x & 63;
    const int g = blockIdx.x * 4 + (threadIdx.x >> 6);   // 0..63
    const float vl = v[lane];
    const int r0 = g * 16;
    #pragma unroll
    for (int i = 0; i < 16; ++i) {
        int row = r0 + i;
        const float* src = (row < D_IN) ? (self_atten + (size_t)row * ATTEN_D)
                                        : (neigh_atten + (size_t)(row - D_IN) * ATTEN_D);
        float p = src[lane] * vl;
        #pragma unroll
        for (int off = 32; off > 0; off >>= 1) p += __shfl_xor(p, off, 64);
        if (lane == 0) {
            if (row < D_IN) u_self[row] = p;
            else            u_neigh[row - D_IN] = p;
        }
    }
}

// ---------------------------------------------------------------------------
// Kernel 1: wave-per-node aggregation, PLUS TR_BLOCKS blocks AT THE FRONT of
// the grid doing the Wt cast+transpose — they launch first, finish early, and
// hide entirely under the 70 us HBM-bound aggregation stream (L2-resident
// 2 MB source). X pad rows NOT zeroed: GEMM A-rows map 1:1 to out rows and
// poison rows only feed accumulators whose stores are guarded (R < N_NODES).
// ---------------------------------------------------------------------------
__global__ __launch_bounds__(256) void aggregate_kernel(
        const float* __restrict__ self_vecs, const float* __restrict__ neigh_vecs,
        const float* __restrict__ neigh_weight, const int* __restrict__ neigh_column,
        const float* __restrict__ alpha,
        const float* __restrict__ u_self, const float* __restrict__ u_neigh,
        unsigned short* __restrict__ X,
        const float* __restrict__ neigh_w, const float* __restrict__ self_w,
        unsigned short* __restrict__ Wt) {
    if (blockIdx.x < TR_BLOCKS) {
        // --- transpose role: Wt[n][k] = (k<512 ? self_w[k][n] : neigh_w[k-512][n]) ---
        int idx = blockIdx.x * blockDim.x + threadIdx.x;
        int stride = TR_BLOCKS * 256;
        for (int i = idx; i < D_OUT * KTOT; i += stride) {
            int n = i >> 10;
            int k = i & (KTOT - 1);
            float w = (k < D_IN) ? self_w[k * D_OUT + n] : neigh_w[(k - D_IN) * D_OUT + n];
            Wt[i] = f2bf(w);
        }
        return;
    }

    const int lane = threadIdx.x & 63;
    const int n = (blockIdx.x - TR_BLOCKS) * 4 + (threadIdx.x >> 6);   // N_NODES % 4 == 0

    // --- softmax coefficients (lanes 0..19 hold coef, rest hold 0) ---
    float e = 0.f, wgt = 0.f;
    if (lane < S_NB) {
        e = expf(alpha[neigh_column[n * S_NB + lane]]);
        wgt = neigh_weight[n * S_NB + lane];
    }
    float ssum = e;
    #pragma unroll
    for (int off = 32; off > 0; off >>= 1) ssum += __shfl_xor(ssum, off, 64);
    float coefv = wgt * e / ssum;

    // --- stream 20 neighbor rows, weighted accumulate ---
    const float4* nb = (const float4*)(neigh_vecs + (size_t)n * S_NB * D_IN);
    float4 acc0 = make_float4(0.f, 0.f, 0.f, 0.f);
    float4 acc1 = make_float4(0.f, 0.f, 0.f, 0.f);
    #pragma unroll
    for (int s = 0; s < S_NB; ++s) {
        float c = __shfl(coefv, s, 64);
        float4 x0 = nb[s * 128 + 2 * lane];
        float4 x1 = nb[s * 128 + 2 * lane + 1];
        acc0.x = fmaf(c, x0.x, acc0.x); acc0.y = fmaf(c, x0.y, acc0.y);
        acc0.z = fmaf(c, x0.z, acc0.z); acc0.w = fmaf(c, x0.w, acc0.w);
        acc1.x = fmaf(c, x1.x, acc1.x); acc1.y = fmaf(c, x1.y, acc1.y);
        acc1.z = fmaf(c, x1.z, acc1.z); acc1.w = fmaf(c, x1.w, acc1.w);
    }

    // --- gate dots (butterfly: every lane ends with the full sums) ---
    const float4* svp = (const float4*)(self_vecs + (size_t)n * D_IN);
    float4 sv0 = svp[2 * lane], sv1 = svp[2 * lane + 1];
    float4 us0 = ((const float4*)u_self)[2 * lane];
    float4 us1 = ((const float4*)u_self)[2 * lane + 1];
    float4 un0 = ((const float4*)u_neigh)[2 * lane];
    float4 un1 = ((const float4*)u_neigh)[2 * lane + 1];
    float p1 = sv0.x * us0.x + sv0.y * us0.y + sv0.z * us0.z + sv0.w * us0.w
             + sv1.x * us1.x + sv1.y * us1.y + sv1.z * us1.z + sv1.w * us1.w;
    float p2 = acc0.x * un0.x + acc0.y * un0.y + acc0.z * un0.z + acc0.w * un0.w
             + acc1.x * un1.x + acc1.y * un1.y + acc1.z * un1.z + acc1.w * un1.w;
    #pragma unroll
    for (int off = 32; off > 0; off >>= 1) {
        p1 += __shfl_xor(p1, off, 64);
        p2 += __shfl_xor(p2, off, 64);
    }
    float a_s = expf(tanhf(2.0f * p1));
    float a_n = expf(tanhf(p2 + p1));
    float inv = 1.0f / (a_s + a_n);
    float gs = a_s * inv, gn = a_n * inv;

    // --- write X row: [gs*self | gn*neigh_sum] as bf16, 16 B per store ---
    unsigned short* xrow = X + (size_t)n * KTOT;
    u16x8 o;
    o[0] = f2bf(gs * sv0.x); o[1] = f2bf(gs * sv0.y);
    o[2] = f2bf(gs * sv0.z); o[3] = f2bf(gs * sv0.w);
    o[4] = f2bf(gs * sv1.x); o[5] = f2bf(gs * sv1.y);
    o[6] = f2bf(gs * sv1.z); o[7] = f2bf(gs * sv1.w);
    *(u16x8*)(xrow + 8 * lane) = o;
    o[0] = f2bf(gn * acc0.x); o[1] = f2bf(gn * acc0.y);
    o[2] = f2bf(gn * acc0.z); o[3] = f2bf(gn * acc0.w);
    o[4] = f2bf(gn * acc1.x); o[5] = f2bf(gn * acc1.y);
    o[6] = f2bf(gn * acc1.z); o[7] = f2bf(gn * acc1.w);
    *(u16x8*)(xrow + D_IN + 8 * lane) = o;
}

// ---------------------------------------------------------------------------
// Kernel 2: out = relu(X[M,1024] @ Wt^T) — 2-phase double-buffered MFMA GEMM.
// BM=64, BN=128, BK=64; 256 threads = 4 waves (2x2, each 32x64); 628 blocks.
// T3-min pipeline: issue next-tile global_load_lds BEFORE current-tile
// compute; ONE barrier per K-step (its implicit vmcnt(0) drain is the wait).
// T2 swizzle: LDS rows are 128 B (16-way conflict if linear); XOR
// byte ^= (row&7)<<4 applied both-sides (pre-swizzled gl_lds SOURCE, linear
// dest; swizzled ds_read offset). row&7 == mrow&7 for every fragment row, so
// the read swizzle is wave-static. LDS 48 KB -> 3 blocks/CU.
// ---------------------------------------------------------------------------
#define BM 64
#define BN 128
#define BK 64

__global__ __launch_bounds__(256) void gemm_kernel(
        const unsigned short* __restrict__ X, const unsigned short* __restrict__ Wt,
        float* __restrict__ out) {
    __shared__ __align__(16) unsigned short As[2][BM * BK];   // 2 x 8 KB
    __shared__ __align__(16) unsigned short Bs[2][BN * BK];   // 2 x 16 KB

    const int tid = threadIdx.x;
    const int lane = tid & 63;
    const int wid = tid >> 6;
    const int m0 = blockIdx.y * BM;
    const int n0 = blockIdx.x * BN;
    const int wm = (wid >> 1) * 32;
    const int wn = (wid & 1) * 64;
    const int quad = lane >> 4;
    const int mrow = lane & 15;

    // --- per-thread staging source offsets (elements), pre-swizzled ---
    // chunk c covers LDS bytes [16c,16c+16): row = c>>3, byte-in-row = (c&7)*16.
    // source byte-in-row = ((c&7)*16) ^ ((row&7)<<4)  (involution within 128 B)
    int srcA[2], srcB[4];
    #pragma unroll
    for (int r = 0; r < 2; ++r) {
        int c = r * 256 + tid;
        int row = c >> 3;
        int sb = ((c & 7) * 16) ^ ((row & 7) << 4);
        srcA[r] = (m0 + row) * KTOT + (sb >> 1);
    }
    #pragma unroll
    for (int r = 0; r < 4; ++r) {
        int c = r * 256 + tid;
        int row = c >> 3;
        int sb = ((c & 7) * 16) ^ ((row & 7) << 4);
        srcB[r] = (n0 + row) * KTOT + (sb >> 1);
    }

    #define STAGE(B_, K0_) {                                                  \
        unsigned short* la_ = &As[B_][0];                                     \
        unsigned short* lb_ = &Bs[B_][0];                                     \
        _Pragma("unroll")                                                     \
        for (int r_ = 0; r_ < 2; ++r_)                                        \
            gl_lds16(X + srcA[r_] + (K0_), la_ + (r_ * 256 + tid) * 8);       \
        _Pragma("unroll")                                                     \
        for (int r_ = 0; r_ < 4; ++r_)                                        \
            gl_lds16(Wt + srcB[r_] + (K0_), lb_ + (r_ * 256 + tid) * 8); }

    f32x4 acc[2][4];
    f32x4 zero = {0.f, 0.f, 0.f, 0.f};
    #pragma unroll
    for (int i = 0; i < 2; ++i)
        #pragma unroll
        for (int j = 0; j < 4; ++j) acc[i][j] = zero;

    const int swz = (mrow & 7) << 4;

    STAGE(0, 0);
    __syncthreads();                       // prologue: buf0 resident

    int cur = 0;
    #pragma unroll 1
    for (int t = 0; t < KTOT / BK; ++t) {
        if (t < KTOT / BK - 1) STAGE(cur ^ 1, (t + 1) * BK);   // in flight across compute

        const char* Ab = (const char*)&As[cur][0];
        const char* Bb = (const char*)&Bs[cur][0];
        #pragma unroll
        for (int s = 0; s < 2; ++s) {
            const int ko = (s * 64 + quad * 16) ^ swz;
            bf16x8 a[2], b[4];
            #pragma unroll
            for (int i = 0; i < 2; ++i)
                a[i] = *(const bf16x8*)(Ab + (wm + i * 16 + mrow) * 128 + ko);
            #pragma unroll
            for (int j = 0; j < 4; ++j)
                b[j] = *(const bf16x8*)(Bb + (wn + j * 16 + mrow) * 128 + ko);
            #pragma unroll
            for (int i = 0; i < 2; ++i)
                #pragma unroll
                for (int j = 0; j < 4; ++j)
                    acc[i][j] = __builtin_amdgcn_mfma_f32_16x16x32_bf16(a[i], b[j], acc[i][j], 0, 0, 0);
        }
        __syncthreads();                   // drains vmcnt(0): next buf resident
        cur ^= 1;
    }
    #undef STAGE

    // epilogue: C/D layout col=lane&15, row=quad*4+reg
    #pragma unroll
    for (int i = 0; i < 2; ++i) {
        int rbase = m0 + wm + i * 16 + quad * 4;
        #pragma unroll
        for (int j = 0; j < 4; ++j) {
            int c = n0 + wn + j * 16 + mrow;
            #pragma unroll
            for (int r = 0; r < 4; ++r) {
                int R = rbase + r;
                if (R < N_NODES)
                    out[(size_t)R * D_OUT + c] = fmaxf(acc[i][j][r], 0.f);
            }
        }
    }
}

extern "C" void kernel_launch(void* const* d_in, const int* in_sizes, int n_in,
                              void* d_out, int out_size, void* d_ws, size_t ws_size,
                              hipStream_t stream) {
    const float* self_vecs     = (const float*)d_in[0];
    const float* neigh_vecs    = (const float*)d_in[1];
    const float* neigh_weight  = (const float*)d_in[2];
    const int*   neigh_column  = (const int*)d_in[3];
    const float* neigh_weights = (const float*)d_in[4];
    const float* self_weights  = (const float*)d_in[5];
    const float* alpha         = (const float*)d_in[6];
    const float* self_atten    = (const float*)d_in[7];
    const float* neigh_atten   = (const float*)d_in[8];
    const float* v             = (const float*)d_in[9];
    float* out = (float*)d_out;

    char* ws = (char*)d_ws;
    float* u_self  = (float*)ws;                                   // 512 f32
    float* u_neigh = u_self + D_IN;                                // 512 f32
    unsigned short* Wt = (unsigned short*)(ws + 4096);             // 512*1024 bf16 = 1 MB
    unsigned short* X  = (unsigned short*)(ws + 4096 + (size_t)D_OUT * KTOT * 2); // M_PAD*1024 bf16

    hipLaunchKernelGGL(u_prep_kernel, dim3(16), dim3(256), 0, stream,
                       self_atten, neigh_atten, v, u_self, u_neigh);
    hipLaunchKernelGGL(aggregate_kernel, dim3(TR_BLOCKS + AGG_BLOCKS), dim3(256), 0, stream,
                       self_vecs, neigh_vecs, neigh_weight, neigh_column, alpha,
                       u_self, u_neigh, X, neigh_weights, self_weights, Wt);
    hipLaunchKernelGGL(gemm_kernel, dim3(D_OUT / BN, M_PAD / BM), dim3(256), 0, stream,
                       X, Wt, out);
}